// Round 3
// baseline (216.648 us; speedup 1.0000x reference)
//
#include <hip/hip_runtime.h>

// Problem constants: B=64, NIN=512, H1=1024, H2=1024, NOUT=512, COND=64, FC=1.
#define BB    64
#define NIN   512
#define H1D   1024
#define H2D   1024
#define NOUTD 512
#define CONDD 64
#define L2E   1.4426950408889634f   // log2(e)

// ---------------------------------------------------------------------------
// Device-scope grid barrier (capture-safe replacement for cooperative sync).
// Counters zeroed per-iteration by hipMemsetAsync before the kernel node.
// Grid is 256 blocks x 1024 thr, 32KB LDS, <=128 VGPR -> 1 block/CU fits on
// all 256 CUs, so all blocks are co-resident and the spin cannot deadlock.
// ---------------------------------------------------------------------------
__device__ __forceinline__ void grid_barrier(unsigned* __restrict__ bar, int phase)
{
    __syncthreads();                       // drains each wave's vmcnt (writes in L2)
    if (threadIdx.x == 0) {
        __threadfence();                   // agent release: L2 writeback
        __hip_atomic_fetch_add(&bar[phase], 1u, __ATOMIC_ACQ_REL,
                               __HIP_MEMORY_SCOPE_AGENT);
        while (__hip_atomic_load(&bar[phase], __ATOMIC_ACQUIRE,
                                 __HIP_MEMORY_SCOPE_AGENT) < 256u) {
            __builtin_amdgcn_s_sleep(8);
        }
        __threadfence();                   // agent acquire: invalidate stale lines
    }
    __syncthreads();                       // hold all waves until visibility done
}

// ---------------------------------------------------------------------------
// Gated masked matvec phase (device body) — identical math to the verified
// round-1 kernels:
//   out[o,b] = sum_i 1/(1+2^(-A'[i,b]*Ct[o,b])) * (m*W)[o,i] * X[i,b]
// 256 blocks x 16 waves; OT o's per block; waves split I 16-ways.
// LDS union: mw tile [OT*I] floats at lds[0], reduction [16*OT*64] after it.
// ---------------------------------------------------------------------------
template<int I, int OT, bool FINAL>
__device__ __forceinline__ void gated_body(
    float* __restrict__ lds,
    const float2* __restrict__ AX, const float* __restrict__ Ct,
    const float*  __restrict__ M,  const float* __restrict__ W,
    float* __restrict__ out, int bid)
{
    constexpr int NW  = 16;                 // waves per block
    constexpr int ICW = I / NW;             // i extent per wave

    const int tid = threadIdx.x;
    const int b   = tid & 63;
    const int wid = __builtin_amdgcn_readfirstlane(tid >> 6);   // 0..15 uniform
    const int o0  = bid * OT;

    float4* __restrict__ mw4 = (float4*)lds;          // OT*I floats
    float*  __restrict__ red = lds + OT * I;          // NW*OT*64 floats

    // --- stage MW = M*W for rows [o0, o0+OT) : contiguous, coalesced ---
    {
        const float4* __restrict__ Mp = (const float4*)(M + (size_t)o0 * I);
        const float4* __restrict__ Wp = (const float4*)(W + (size_t)o0 * I);
        for (int e = tid; e < (OT * I) / 4; e += NW * 64) {
            const float4 a = Mp[e];
            const float4 c = Wp[e];
            float4 r;
            r.x = a.x * c.x; r.y = a.y * c.y; r.z = a.z * c.z; r.w = a.w * c.w;
            mw4[e] = r;
        }
    }

    float cc[OT], acc[OT];
    #pragma unroll
    for (int oo = 0; oo < OT; ++oo) {
        cc[oo]  = Ct[(o0 + oo) * 64 + b];
        acc[oo] = 0.f;
    }
    __syncthreads();

    const int ibase = wid * ICW;
    const float*  __restrict__ mwp = lds + ibase;               // + oo*I + ii
    const float2* __restrict__ axp = AX + (size_t)ibase * 64 + b;

    #pragma unroll 8
    for (int ii = 0; ii < ICW; ++ii) {
        const float2 ax = axp[(size_t)ii * 64];
        #pragma unroll
        for (int oo = 0; oo < OT; ++oo) {
            const float mw = mwp[oo * I + ii];                  // LDS broadcast
            const float t  = __builtin_amdgcn_exp2f(-(ax.x * cc[oo]));
            const float s  = __builtin_amdgcn_rcpf(1.f + t);    // inf-safe: ->0
            acc[oo] = fmaf(s, mw * ax.y, acc[oo]);
        }
    }

    #pragma unroll
    for (int oo = 0; oo < OT; ++oo) red[(wid * OT + oo) * 64 + b] = acc[oo];
    __syncthreads();
    if (tid < OT * 64) {
        const int oo = tid >> 6, bb = tid & 63;
        float v = 0.f;
        #pragma unroll
        for (int w16 = 0; w16 < NW; ++w16) v += red[(w16 * OT + oo) * 64 + bb];
        if (FINAL) out[bb * NOUTD + (o0 + oo)] = v;             // (B, NOUT)
        else       out[((o0 + oo) * 64 + bb) * 2 + 1] = v;      // next AX .y
    }
}

// ---------------------------------------------------------------------------
// Fully fused kernel: 256 blocks x 1024 threads (1 block/CU, co-resident).
// Phase 0 (prep): blocks 0..79 do the six cond GEMMs (64 rows/block,
//   4 rows/wave, rows concatenated [A0|C0|A1|C1|A2|C2] = 5120);
//   blocks 80..87 transpose x into AX0 .y; blocks 88..255 idle.
// grid_barrier between phases replaces 3 kernel boundaries.
// ---------------------------------------------------------------------------
__global__ __launch_bounds__(1024) void fused_kernel(
    const float* __restrict__ x,  const float* __restrict__ u,
    const float* __restrict__ a0w, const float* __restrict__ a0b,
    const float* __restrict__ b0w, const float* __restrict__ b0b,
    const float* __restrict__ a1w, const float* __restrict__ a1b,
    const float* __restrict__ b1w, const float* __restrict__ b1b,
    const float* __restrict__ a2w, const float* __restrict__ a2b,
    const float* __restrict__ b2w, const float* __restrict__ b2b,
    const float* __restrict__ m0, const float* __restrict__ W0,
    const float* __restrict__ m1, const float* __restrict__ W1,
    const float* __restrict__ m2, const float* __restrict__ W2,
    float* __restrict__ AX0, float* __restrict__ AX1, float* __restrict__ AX2,
    float* __restrict__ C0t, float* __restrict__ C1t, float* __restrict__ C2t,
    unsigned* __restrict__ bar, float* __restrict__ out)
{
    __shared__ float lds[8192];           // 32 KB union across phases
    const int tid = threadIdx.x;
    const int bid = blockIdx.x;

    // ---------------- phase 0: prep ----------------
    if (bid < 80) {
        // stage u transposed: lds[k*65+b] = u[b*64+k]
        for (int e = tid; e < BB * CONDD; e += 1024)
            lds[(e & 63) * 65 + (e >> 6)] = u[e];
        __syncthreads();

        const int b   = tid & 63;
        const int wid = __builtin_amdgcn_readfirstlane(tid >> 6);   // 0..15
        const int r0  = bid * 64 + wid * 4;          // 4 rows per wave

        const float* w; const float* bias; float* o; int stride; float scale; int lr0;
        if      (r0 <  512) { w = a0w; bias = a0b; o = AX0; stride = 2; scale = L2E; lr0 = r0;        }
        else if (r0 < 1536) { w = b0w; bias = b0b; o = C0t; stride = 1; scale = 1.f; lr0 = r0 -  512; }
        else if (r0 < 2560) { w = a1w; bias = a1b; o = AX1; stride = 2; scale = L2E; lr0 = r0 - 1536; }
        else if (r0 < 3584) { w = b1w; bias = b1b; o = C1t; stride = 1; scale = 1.f; lr0 = r0 - 2560; }
        else if (r0 < 4608) { w = a2w; bias = a2b; o = AX2; stride = 2; scale = L2E; lr0 = r0 - 3584; }
        else                { w = b2w; bias = b2b; o = C2t; stride = 1; scale = 1.f; lr0 = r0 - 4608; }

        const float* __restrict__ w0 = w + (lr0 + 0) * CONDD;
        const float* __restrict__ w1 = w + (lr0 + 1) * CONDD;
        const float* __restrict__ w2 = w + (lr0 + 2) * CONDD;
        const float* __restrict__ w3 = w + (lr0 + 3) * CONDD;
        float acc0 = bias[lr0 + 0], acc1 = bias[lr0 + 1];
        float acc2 = bias[lr0 + 2], acc3 = bias[lr0 + 3];
        #pragma unroll
        for (int k = 0; k < CONDD; ++k) {
            const float uv = lds[k * 65 + b];
            acc0 = fmaf(w0[k], uv, acc0);
            acc1 = fmaf(w1[k], uv, acc1);
            acc2 = fmaf(w2[k], uv, acc2);
            acc3 = fmaf(w3[k], uv, acc3);
        }
        o[((lr0 + 0) * 64 + b) * stride] = acc0 * scale;
        o[((lr0 + 1) * 64 + b) * stride] = acc1 * scale;
        o[((lr0 + 2) * 64 + b) * stride] = acc2 * scale;
        o[((lr0 + 3) * 64 + b) * stride] = acc3 * scale;
    } else if (bid < 88) {
        // transpose one 64(b) x 64(i) tile of x into AX0 .y slots
        const int i0 = (bid - 80) * 64;
        for (int e = tid; e < 64 * 64; e += 1024) {
            int r = e >> 6, c = e & 63;                // r=b, c=i offset
            lds[c * 65 + r] = x[r * NIN + i0 + c];
        }
        __syncthreads();
        for (int e = tid; e < 64 * 64; e += 1024) {
            int r = e >> 6, c = e & 63;                // r=i offset, c=b
            AX0[((i0 + r) * 64 + c) * 2 + 1] = lds[r * 65 + c];
        }
    }

    grid_barrier(bar, 0);
    // ---------------- phase 1: L1 (I=512,  O=1024, OT=4) ----------------
    gated_body<NIN, 4, false>(lds, (const float2*)AX0, C0t, m0, W0, AX1, bid);
    grid_barrier(bar, 1);
    // ---------------- phase 2: L2 (I=1024, O=1024, OT=4) ----------------
    gated_body<H1D, 4, false>(lds, (const float2*)AX1, C1t, m1, W1, AX2, bid);
    grid_barrier(bar, 2);
    // ---------------- phase 3: L3 (I=1024, O=512, OT=2) -> d_out --------
    gated_body<H2D, 2, true>(lds, (const float2*)AX2, C2t, m2, W2, out, bid);
}

// ---------------------------------------------------------------------------
extern "C" void kernel_launch(void* const* d_in, const int* in_sizes, int n_in,
                              void* d_out, int out_size, void* d_ws, size_t ws_size,
                              hipStream_t stream) {
    (void)in_sizes; (void)n_in; (void)out_size; (void)ws_size;
    const float* x   = (const float*)d_in[0];
    const float* u   = (const float*)d_in[1];
    const float* m0  = (const float*)d_in[2];
    const float* m1  = (const float*)d_in[3];
    const float* m2  = (const float*)d_in[4];
    const float* W0  = (const float*)d_in[5];
    const float* W1  = (const float*)d_in[6];
    const float* W2  = (const float*)d_in[7];
    const float* a0w = (const float*)d_in[8];  const float* a0b = (const float*)d_in[9];
    const float* b0w = (const float*)d_in[10]; const float* b0b = (const float*)d_in[11];
    const float* a1w = (const float*)d_in[12]; const float* a1b = (const float*)d_in[13];
    const float* b1w = (const float*)d_in[14]; const float* b1b = (const float*)d_in[15];
    const float* a2w = (const float*)d_in[16]; const float* a2b = (const float*)d_in[17];
    const float* b2w = (const float*)d_in[18]; const float* b2b = (const float*)d_in[19];

    float* ws  = (float*)d_ws;                 // offsets in floats
    float* AX0 = ws;                           // float2[512*64]   = 65536
    float* AX1 = ws + 65536;                   // float2[1024*64]  = 131072
    float* AX2 = ws + 196608;                  // float2[1024*64]  = 131072
    float* C0t = ws + 327680;                  // 1024*64 = 65536
    float* C1t = ws + 393216;                  // 1024*64 = 65536
    float* C2t = ws + 458752;                  // 512*64  = 32768
    unsigned* bar = (unsigned*)(ws + 524288);  // barrier counters @ 2MB
    float* out = (float*)d_out;

    // re-arm barrier counters each replay (workspace is poisoned between iters)
    hipMemsetAsync((void*)bar, 0, 64, stream);

    void* args[] = {
        (void*)&x, (void*)&u,
        (void*)&a0w, (void*)&a0b, (void*)&b0w, (void*)&b0b,
        (void*)&a1w, (void*)&a1b, (void*)&b1w, (void*)&b1b,
        (void*)&a2w, (void*)&a2b, (void*)&b2w, (void*)&b2b,
        (void*)&m0, (void*)&W0, (void*)&m1, (void*)&W1, (void*)&m2, (void*)&W2,
        (void*)&AX0, (void*)&AX1, (void*)&AX2,
        (void*)&C0t, (void*)&C1t, (void*)&C2t,
        (void*)&bar, (void*)&out
    };
    (void)args;
    fused_kernel<<<256, 1024, 0, stream>>>(x, u,
        a0w, a0b, b0w, b0b, a1w, a1b, b1w, b1b, a2w, a2b, b2w, b2b,
        m0, W0, m1, W1, m2, W2,
        AX0, AX1, AX2, C0t, C1t, C2t, bar, out);
}

// Round 4
// 144.129 us; speedup vs baseline: 1.5031x; 1.5031x over previous
//
#include <hip/hip_runtime.h>

// Problem constants: B=64, NIN=512, H1=1024, H2=1024, NOUT=512, COND=64, FC=1.
#define BB    64
#define NIN   512
#define H1D   1024
#define H2D   1024
#define NOUTD 512
#define CONDD 64
#define L2E   1.4426950408889634f   // log2(e)

// ---------------------------------------------------------------------------
// Prep kernel (grid 504 x 256 thr):
//   bids [0,320)   : six cond GEMMs, 16 rows/block (4 rows/wave), rows
//                    concatenated [A0|C0|A1|C1|A2|C2] = 5120 rows.
//                    A-rows prescaled by log2(e) into AX .x (stride 2).
//   bids [320,328) : x transpose tiles -> AX0 .y
//   bids [328,392) : m0 row sums  -> len1 (= d1, also sort key for h1)
//   bids [392,456) : m1 row sums  -> len2 (layer-2 prefix length per h2)
//   bids [456,488) : m2 row sums  -> len3 (layer-3 prefix length per o)
//   bids [488,504) : m2 col sums  -> key2 (= d2 = 512 - colsum, h2 sort key)
// ---------------------------------------------------------------------------
__global__ __launch_bounds__(256) void prep_kernel(
    const float* __restrict__ x,  const float* __restrict__ u,
    const float* __restrict__ a0w, const float* __restrict__ a0b,
    const float* __restrict__ b0w, const float* __restrict__ b0b,
    const float* __restrict__ a1w, const float* __restrict__ a1b,
    const float* __restrict__ b1w, const float* __restrict__ b1b,
    const float* __restrict__ a2w, const float* __restrict__ a2b,
    const float* __restrict__ b2w, const float* __restrict__ b2b,
    const float* __restrict__ m0, const float* __restrict__ m1,
    const float* __restrict__ m2,
    float* __restrict__ AX0, float* __restrict__ AX1, float* __restrict__ AX2,
    float* __restrict__ C0t, float* __restrict__ C1t, float* __restrict__ C2t,
    int* __restrict__ len1, int* __restrict__ len2, int* __restrict__ len3,
    int* __restrict__ key2)
{
    __shared__ float lds[64 * 65];
    const int tid = threadIdx.x;
    const int bid = blockIdx.x;

    if (bid < 320) {
        // stage u transposed: lds[k*65+b] = u[b*64+k]
        for (int e = tid; e < BB * CONDD; e += 256)
            lds[(e & 63) * 65 + (e >> 6)] = u[e];
        __syncthreads();

        const int b   = tid & 63;
        const int wid = __builtin_amdgcn_readfirstlane(tid >> 6);
        const int r0  = bid * 16 + wid * 4;          // 4 rows per wave

        const float* w; const float* bias; float* o; int stride; float scale; int lr0;
        if      (r0 <  512) { w = a0w; bias = a0b; o = AX0; stride = 2; scale = L2E; lr0 = r0;        }
        else if (r0 < 1536) { w = b0w; bias = b0b; o = C0t; stride = 1; scale = 1.f; lr0 = r0 -  512; }
        else if (r0 < 2560) { w = a1w; bias = a1b; o = AX1; stride = 2; scale = L2E; lr0 = r0 - 1536; }
        else if (r0 < 3584) { w = b1w; bias = b1b; o = C1t; stride = 1; scale = 1.f; lr0 = r0 - 2560; }
        else if (r0 < 4608) { w = a2w; bias = a2b; o = AX2; stride = 2; scale = L2E; lr0 = r0 - 3584; }
        else                { w = b2w; bias = b2b; o = C2t; stride = 1; scale = 1.f; lr0 = r0 - 4608; }

        const float* __restrict__ w0 = w + (lr0 + 0) * CONDD;
        const float* __restrict__ w1 = w + (lr0 + 1) * CONDD;
        const float* __restrict__ w2 = w + (lr0 + 2) * CONDD;
        const float* __restrict__ w3 = w + (lr0 + 3) * CONDD;
        float acc0 = bias[lr0 + 0], acc1 = bias[lr0 + 1];
        float acc2 = bias[lr0 + 2], acc3 = bias[lr0 + 3];
        #pragma unroll
        for (int k = 0; k < CONDD; ++k) {
            const float uv = lds[k * 65 + b];
            acc0 = fmaf(w0[k], uv, acc0);
            acc1 = fmaf(w1[k], uv, acc1);
            acc2 = fmaf(w2[k], uv, acc2);
            acc3 = fmaf(w3[k], uv, acc3);
        }
        o[((lr0 + 0) * 64 + b) * stride] = acc0 * scale;
        o[((lr0 + 1) * 64 + b) * stride] = acc1 * scale;
        o[((lr0 + 2) * 64 + b) * stride] = acc2 * scale;
        o[((lr0 + 3) * 64 + b) * stride] = acc3 * scale;
    } else if (bid < 328) {
        // transpose one 64(b) x 64(i) tile of x into AX0 .y slots
        const int i0 = (bid - 320) * 64;
        for (int e = tid; e < 64 * 64; e += 256) {
            int r = e >> 6, c = e & 63;                // r=b, c=i offset
            lds[c * 65 + r] = x[r * NIN + i0 + c];
        }
        __syncthreads();
        for (int e = tid; e < 64 * 64; e += 256) {
            int r = e >> 6, c = e & 63;                // r=i offset, c=b
            AX0[((i0 + r) * 64 + c) * 2 + 1] = lds[r * 65 + c];
        }
    } else if (bid < 392) {
        // m0 row sums -> len1 (rows 512 wide)
        const int l = tid & 63, w = tid >> 6;
        const int rb = (bid - 328) * 16 + w * 4;
        for (int j = 0; j < 4; ++j) {
            const int r = rb + j;
            const float4* rp = (const float4*)(m0 + (size_t)r * 512);
            const float4 A = rp[l], B = rp[l + 64];
            float s = A.x + A.y + A.z + A.w + B.x + B.y + B.z + B.w;
            #pragma unroll
            for (int d = 32; d; d >>= 1) s += __shfl_down(s, d);
            if (l == 0) len1[r] = (int)(s + 0.5f);
        }
    } else if (bid < 456) {
        // m1 row sums -> len2 (rows 1024 wide)
        const int l = tid & 63, w = tid >> 6;
        const int rb = (bid - 392) * 16 + w * 4;
        for (int j = 0; j < 4; ++j) {
            const int r = rb + j;
            const float4* rp = (const float4*)(m1 + (size_t)r * 1024);
            const float4 A = rp[l], B = rp[l + 64], C = rp[l + 128], D = rp[l + 192];
            float s = A.x + A.y + A.z + A.w + B.x + B.y + B.z + B.w
                    + C.x + C.y + C.z + C.w + D.x + D.y + D.z + D.w;
            #pragma unroll
            for (int d = 32; d; d >>= 1) s += __shfl_down(s, d);
            if (l == 0) len2[r] = (int)(s + 0.5f);
        }
    } else if (bid < 488) {
        // m2 row sums -> len3 (512 rows, 1024 wide)
        const int l = tid & 63, w = tid >> 6;
        const int rb = (bid - 456) * 16 + w * 4;
        for (int j = 0; j < 4; ++j) {
            const int r = rb + j;
            const float4* rp = (const float4*)(m2 + (size_t)r * 1024);
            const float4 A = rp[l], B = rp[l + 64], C = rp[l + 128], D = rp[l + 192];
            float s = A.x + A.y + A.z + A.w + B.x + B.y + B.z + B.w
                    + C.x + C.y + C.z + C.w + D.x + D.y + D.z + D.w;
            #pragma unroll
            for (int d = 32; d; d >>= 1) s += __shfl_down(s, d);
            if (l == 0) len3[r] = (int)(s + 0.5f);
        }
    } else {
        // m2 col sums -> key2 = d2 = 512 - colsum  (1024 cols, 512 rows)
        const int cb  = bid - 488;
        const int c   = cb * 64 + (tid & 63);
        const int seg = tid >> 6;                    // 0..3, 128 rows each
        float s = 0.f;
        for (int j = 0; j < 128; ++j)
            s += m2[(size_t)(seg * 128 + j) * 1024 + c];
        lds[seg * 64 + (tid & 63)] = s;
        __syncthreads();
        if (tid < 64) {
            const float t = lds[tid] + lds[64 + tid] + lds[128 + tid] + lds[192 + tid];
            key2[cb * 64 + tid] = 512 - (int)(t + 0.5f);
        }
    }
}

// ---------------------------------------------------------------------------
// Counting sort (2 blocks x 1024 thr). Keys < 1024. Not stable (ties broken
// by atomic order) — any consistent bijection works for the prefix property.
//   block 0: sort h1 by len1 (=d1)  -> order1, len1s (sorted lens)
//   block 1: sort h2 by key2 (=d2)  -> order2, len2s[pos] = len2[orig]
// ---------------------------------------------------------------------------
__global__ __launch_bounds__(1024) void sort_kernel(
    const int* __restrict__ len1, const int* __restrict__ key2,
    const int* __restrict__ len2,
    int* __restrict__ order1, int* __restrict__ len1s,
    int* __restrict__ order2, int* __restrict__ len2s)
{
    __shared__ int hist[1024];
    __shared__ int scan[1024];
    const int t = threadIdx.x;
    const int* key = blockIdx.x ? key2 : len1;
    const int k = key[t];
    hist[t] = 0;
    __syncthreads();
    atomicAdd(&hist[k], 1);
    __syncthreads();
    scan[t] = hist[t];
    __syncthreads();
    for (int s = 1; s < 1024; s <<= 1) {
        const int v = scan[t] + ((t >= s) ? scan[t - s] : 0);
        __syncthreads();
        scan[t] = v;
        __syncthreads();
    }
    const int excl = scan[t] - hist[t];       // exclusive base for bin t
    __syncthreads();
    hist[t] = excl;                            // hist becomes cursor
    __syncthreads();
    const int pos = atomicAdd(&hist[k], 1);
    if (blockIdx.x == 0) {
        order1[pos] = t;
        len1s[pos]  = k;                       // len1 IS the key
    } else {
        order2[pos] = t;
        len2s[pos]  = len2[t];                 // monotone in d2 -> sorted
    }
}

// ---------------------------------------------------------------------------
// Gated masked matvec with prefix sparsity:
//   out[o,b] = sum_{p<len(o)} sigmoid-gate(A'[ix,b]*Ct[o,b]) * W[o,ix] * X[ix,b]
//   where ix = ordIn[p] (sorted input order) and masked entries (p>=len) drop.
// Grid O/2 blocks x 1024 thr (16 waves); 2 output rows/block (consecutive
// sorted positions -> near-equal lens). Waves stride the prefix by 16.
// Mirror bid->pair map balances per-CU load under round-robin assignment.
// ---------------------------------------------------------------------------
template<int I, int O, bool PR, bool GI, bool FINAL>
__global__ __launch_bounds__(1024) void gated(
    const float2* __restrict__ AX, const float* __restrict__ Ct,
    const float* __restrict__ W,  const int* __restrict__ lenS,
    const int* __restrict__ ordRow, const int* __restrict__ ordIn,
    float* __restrict__ out)
{
    constexpr int NB = O / 2;
    const int bid = blockIdx.x;
    const int k   = (bid < NB / 2) ? bid : (NB + NB / 2 - 1 - bid);  // mirror
    const int R0  = 2 * k;
    const int tid = threadIdx.x;
    const int b   = tid & 63;
    const int wid = __builtin_amdgcn_readfirstlane(tid >> 6);

    __shared__ float2 mw[I];
    __shared__ int    ord[GI ? I : 1];
    __shared__ float  red[16][2][64];

    const int len0 = lenS[R0], len1 = lenS[R0 + 1];
    const int r0 = PR ? ordRow[R0]     : R0;
    const int r1 = PR ? ordRow[R0 + 1] : (R0 + 1);
    const int Lb  = (len0 > len1) ? len0 : len1;
    const int T   = (Lb + 15) >> 4;
    const int T16 = T << 4;                    // <= I always (len <= I)

    const float* __restrict__ w0p = W + (size_t)r0 * I;
    const float* __restrict__ w1p = W + (size_t)r1 * I;
    for (int p = tid; p < T16; p += 1024) {
        const int ix = GI ? ordIn[p] : p;
        if (GI) ord[p] = ix;
        float2 v;
        v.x = (p < len0) ? w0p[ix] : 0.f;      // mask: zero beyond prefix
        v.y = (p < len1) ? w1p[ix] : 0.f;
        mw[p] = v;
    }
    const float cc0 = Ct[r0 * 64 + b];
    const float cc1 = Ct[r1 * 64 + b];
    __syncthreads();

    float a0 = 0.f, a1 = 0.f;
    #pragma unroll 4
    for (int t = 0; t < T; ++t) {
        const int p  = wid + (t << 4);
        const int ix = GI ? ord[p] : p;
        const float2 ax = AX[(size_t)ix * 64 + b];   // coalesced (uniform ix)
        const float2 w  = mw[p];                     // LDS broadcast
        const float e0 = __builtin_amdgcn_exp2f(-(ax.x * cc0));
        const float s0 = __builtin_amdgcn_rcpf(1.f + e0);   // inf-safe -> 0
        const float e1 = __builtin_amdgcn_exp2f(-(ax.x * cc1));
        const float s1 = __builtin_amdgcn_rcpf(1.f + e1);
        a0 = fmaf(s0, w.x * ax.y, a0);
        a1 = fmaf(s1, w.y * ax.y, a1);
    }

    red[wid][0][b] = a0;
    red[wid][1][b] = a1;
    __syncthreads();
    if (tid < 128) {
        const int oo = tid >> 6, bb = tid & 63;
        float v = 0.f;
        #pragma unroll
        for (int q = 0; q < 16; ++q) v += red[q][oo][bb];
        const int r = oo ? r1 : r0;               // original row id
        if (FINAL) out[bb * NOUTD + r] = v;       // (B, NOUT)
        else       out[((size_t)r * 64 + bb) * 2 + 1] = v;  // next AX .y (natural slot)
    }
}

// ---------------------------------------------------------------------------
extern "C" void kernel_launch(void* const* d_in, const int* in_sizes, int n_in,
                              void* d_out, int out_size, void* d_ws, size_t ws_size,
                              hipStream_t stream) {
    (void)in_sizes; (void)n_in; (void)out_size; (void)ws_size;
    const float* x   = (const float*)d_in[0];
    const float* u   = (const float*)d_in[1];
    const float* m0  = (const float*)d_in[2];
    const float* m1  = (const float*)d_in[3];
    const float* m2  = (const float*)d_in[4];
    const float* W0  = (const float*)d_in[5];
    const float* W1  = (const float*)d_in[6];
    const float* W2  = (const float*)d_in[7];
    const float* a0w = (const float*)d_in[8];  const float* a0b = (const float*)d_in[9];
    const float* b0w = (const float*)d_in[10]; const float* b0b = (const float*)d_in[11];
    const float* a1w = (const float*)d_in[12]; const float* a1b = (const float*)d_in[13];
    const float* b1w = (const float*)d_in[14]; const float* b1b = (const float*)d_in[15];
    const float* a2w = (const float*)d_in[16]; const float* a2b = (const float*)d_in[17];
    const float* b2w = (const float*)d_in[18]; const float* b2b = (const float*)d_in[19];

    float* ws  = (float*)d_ws;                 // offsets in floats
    float* AX0 = ws;                           // float2[512*64]   = 65536
    float* AX1 = ws + 65536;                   // float2[1024*64]  = 131072
    float* AX2 = ws + 196608;                  // float2[1024*64]  = 131072
    float* C0t = ws + 327680;                  // 1024*64 = 65536
    float* C1t = ws + 393216;                  // 1024*64 = 65536
    float* C2t = ws + 458752;                  // 512*64  = 32768
    int*   ib  = (int*)(ws + 491520);
    int* len1   = ib;                          // 1024
    int* len2   = ib + 1024;                   // 1024
    int* len3   = ib + 2048;                   // 512
    int* key2   = ib + 2560;                   // 1024
    int* order1 = ib + 3584;                   // 1024
    int* len1s  = ib + 4608;                   // 1024
    int* order2 = ib + 5632;                   // 1024
    int* len2s  = ib + 6656;                   // 1024
    float* out = (float*)d_out;

    prep_kernel<<<504, 256, 0, stream>>>(x, u,
        a0w, a0b, b0w, b0b, a1w, a1b, b1w, b1b, a2w, a2b, b2w, b2b,
        m0, m1, m2,
        AX0, AX1, AX2, C0t, C1t, C2t,
        len1, len2, len3, key2);

    sort_kernel<<<2, 1024, 0, stream>>>(len1, key2, len2,
                                        order1, len1s, order2, len2s);

    // L1: I=512,  O=1024; rows = order1[R] (sorted by d1); input dim natural
    gated<NIN, H1D, true,  false, false><<<H1D / 2, 1024, 0, stream>>>(
        (const float2*)AX0, C0t, W0, len1s, order1, nullptr, AX1);
    // L2: I=1024, O=1024; rows = order2[R] (sorted by d2); input gathered by order1
    gated<H1D, H2D, true,  true,  false><<<H2D / 2, 1024, 0, stream>>>(
        (const float2*)AX1, C1t, W1, len2s, order2, order1, AX2);
    // L3: I=1024, O=512;  rows natural (len3 ascending in o); input gathered by order2
    gated<H2D, NOUTD, false, true, true><<<NOUTD / 2, 1024, 0, stream>>>(
        (const float2*)AX2, C2t, W2, len3, nullptr, order2, out);
}

// Round 5
// 140.726 us; speedup vs baseline: 1.5395x; 1.0242x over previous
//
#include <hip/hip_runtime.h>

// Problem constants: B=64, NIN=512, H1=1024, H2=1024, NOUT=512, COND=64, FC=1.
#define BB    64
#define NIN   512
#define H1D   1024
#define H2D   1024
#define NOUTD 512
#define CONDD 64
#define L2E   1.4426950408889634f   // log2(e)

// ---------------------------------------------------------------------------
// Prep kernel (grid 504 x 256 thr):
//   bids [0,320)   : six cond GEMMs, 16 rows/block (4 rows/wave), rows
//                    concatenated [A0|C0|A1|C1|A2|C2] = 5120 rows.
//                    A0 -> AX0 .x (stride 2, *L2E); A1,A2 -> plain arrays
//                    A1x,A2x (stride 1, *L2E); C* -> C*t (stride 1).
//   bids [320,328) : x transpose tiles -> AX0 .y
//   bids [328,392) : m0 row sums  -> len1 (= d1, h1 sort key)
//   bids [392,456) : m1 row sums  -> len2 (layer-2 prefix length per h2)
//   bids [456,488) : m2 row sums  -> len3 (layer-3 prefix length per o)
//   bids [488,504) : m2 col sums  -> key2 (= d2, h2 sort key)
// ---------------------------------------------------------------------------
__global__ __launch_bounds__(256) void prep_kernel(
    const float* __restrict__ x,  const float* __restrict__ u,
    const float* __restrict__ a0w, const float* __restrict__ a0b,
    const float* __restrict__ b0w, const float* __restrict__ b0b,
    const float* __restrict__ a1w, const float* __restrict__ a1b,
    const float* __restrict__ b1w, const float* __restrict__ b1b,
    const float* __restrict__ a2w, const float* __restrict__ a2b,
    const float* __restrict__ b2w, const float* __restrict__ b2b,
    const float* __restrict__ m0, const float* __restrict__ m1,
    const float* __restrict__ m2,
    float* __restrict__ AX0, float* __restrict__ A1x, float* __restrict__ A2x,
    float* __restrict__ C0t, float* __restrict__ C1t, float* __restrict__ C2t,
    int* __restrict__ len1, int* __restrict__ len2, int* __restrict__ len3,
    int* __restrict__ key2)
{
    __shared__ float lds[64 * 65];
    const int tid = threadIdx.x;
    const int bid = blockIdx.x;

    if (bid < 320) {
        // stage u transposed: lds[k*65+b] = u[b*64+k]
        for (int e = tid; e < BB * CONDD; e += 256)
            lds[(e & 63) * 65 + (e >> 6)] = u[e];
        __syncthreads();

        const int b   = tid & 63;
        const int wid = __builtin_amdgcn_readfirstlane(tid >> 6);
        const int r0  = bid * 16 + wid * 4;          // 4 rows per wave

        const float* w; const float* bias; float* o; int stride; float scale; int lr0;
        if      (r0 <  512) { w = a0w; bias = a0b; o = AX0; stride = 2; scale = L2E; lr0 = r0;        }
        else if (r0 < 1536) { w = b0w; bias = b0b; o = C0t; stride = 1; scale = 1.f; lr0 = r0 -  512; }
        else if (r0 < 2560) { w = a1w; bias = a1b; o = A1x; stride = 1; scale = L2E; lr0 = r0 - 1536; }
        else if (r0 < 3584) { w = b1w; bias = b1b; o = C1t; stride = 1; scale = 1.f; lr0 = r0 - 2560; }
        else if (r0 < 4608) { w = a2w; bias = a2b; o = A2x; stride = 1; scale = L2E; lr0 = r0 - 3584; }
        else                { w = b2w; bias = b2b; o = C2t; stride = 1; scale = 1.f; lr0 = r0 - 4608; }

        const float* __restrict__ w0 = w + (lr0 + 0) * CONDD;
        const float* __restrict__ w1 = w + (lr0 + 1) * CONDD;
        const float* __restrict__ w2 = w + (lr0 + 2) * CONDD;
        const float* __restrict__ w3 = w + (lr0 + 3) * CONDD;
        float acc0 = bias[lr0 + 0], acc1 = bias[lr0 + 1];
        float acc2 = bias[lr0 + 2], acc3 = bias[lr0 + 3];
        #pragma unroll
        for (int k = 0; k < CONDD; ++k) {
            const float uv = lds[k * 65 + b];
            acc0 = fmaf(w0[k], uv, acc0);
            acc1 = fmaf(w1[k], uv, acc1);
            acc2 = fmaf(w2[k], uv, acc2);
            acc3 = fmaf(w3[k], uv, acc3);
        }
        o[((lr0 + 0) * 64 + b) * stride] = acc0 * scale;
        o[((lr0 + 1) * 64 + b) * stride] = acc1 * scale;
        o[((lr0 + 2) * 64 + b) * stride] = acc2 * scale;
        o[((lr0 + 3) * 64 + b) * stride] = acc3 * scale;
    } else if (bid < 328) {
        // transpose one 64(b) x 64(i) tile of x into AX0 .y slots
        const int i0 = (bid - 320) * 64;
        for (int e = tid; e < 64 * 64; e += 256) {
            int r = e >> 6, c = e & 63;                // r=b, c=i offset
            lds[c * 65 + r] = x[r * NIN + i0 + c];
        }
        __syncthreads();
        for (int e = tid; e < 64 * 64; e += 256) {
            int r = e >> 6, c = e & 63;                // r=i offset, c=b
            AX0[((i0 + r) * 64 + c) * 2 + 1] = lds[r * 65 + c];
        }
    } else if (bid < 392) {
        // m0 row sums -> len1 (rows 512 wide)
        const int l = tid & 63, w = tid >> 6;
        const int rb = (bid - 328) * 16 + w * 4;
        for (int j = 0; j < 4; ++j) {
            const int r = rb + j;
            const float4* rp = (const float4*)(m0 + (size_t)r * 512);
            const float4 A = rp[l], B = rp[l + 64];
            float s = A.x + A.y + A.z + A.w + B.x + B.y + B.z + B.w;
            #pragma unroll
            for (int d = 32; d; d >>= 1) s += __shfl_down(s, d);
            if (l == 0) len1[r] = (int)(s + 0.5f);
        }
    } else if (bid < 456) {
        // m1 row sums -> len2 (rows 1024 wide)
        const int l = tid & 63, w = tid >> 6;
        const int rb = (bid - 392) * 16 + w * 4;
        for (int j = 0; j < 4; ++j) {
            const int r = rb + j;
            const float4* rp = (const float4*)(m1 + (size_t)r * 1024);
            const float4 A = rp[l], B = rp[l + 64], C = rp[l + 128], D = rp[l + 192];
            float s = A.x + A.y + A.z + A.w + B.x + B.y + B.z + B.w
                    + C.x + C.y + C.z + C.w + D.x + D.y + D.z + D.w;
            #pragma unroll
            for (int d = 32; d; d >>= 1) s += __shfl_down(s, d);
            if (l == 0) len2[r] = (int)(s + 0.5f);
        }
    } else if (bid < 488) {
        // m2 row sums -> len3 (512 rows, 1024 wide)
        const int l = tid & 63, w = tid >> 6;
        const int rb = (bid - 456) * 16 + w * 4;
        for (int j = 0; j < 4; ++j) {
            const int r = rb + j;
            const float4* rp = (const float4*)(m2 + (size_t)r * 1024);
            const float4 A = rp[l], B = rp[l + 64], C = rp[l + 128], D = rp[l + 192];
            float s = A.x + A.y + A.z + A.w + B.x + B.y + B.z + B.w
                    + C.x + C.y + C.z + C.w + D.x + D.y + D.z + D.w;
            #pragma unroll
            for (int d = 32; d; d >>= 1) s += __shfl_down(s, d);
            if (l == 0) len3[r] = (int)(s + 0.5f);
        }
    } else {
        // m2 col sums -> key2 = d2 = 512 - colsum  (1024 cols, 512 rows)
        const int cb  = bid - 488;
        const int c   = cb * 64 + (tid & 63);
        const int seg = tid >> 6;                    // 0..3, 128 rows each
        float s = 0.f;
        for (int j = 0; j < 128; ++j)
            s += m2[(size_t)(seg * 128 + j) * 1024 + c];
        lds[seg * 64 + (tid & 63)] = s;
        __syncthreads();
        if (tid < 64) {
            const float t = lds[tid] + lds[64 + tid] + lds[128 + tid] + lds[192 + tid];
            key2[cb * 64 + tid] = 512 - (int)(t + 0.5f);
        }
    }
}

// ---------------------------------------------------------------------------
// Counting sort + pad-zeroing (3 blocks x 1024 thr). Keys < 1024.
//   block 0: sort h1 by len1 (=d1)  -> order1, len1s (sorted lens)
//   block 1: sort h2 by key2 (=d2)  -> order2, len2s[pos] = len2[orig]
//   block 2: zero the AX pad regions (poisoned each iter; pads must be 0
//            so out-of-prefix gate terms contribute exactly 0, not NaN)
// ---------------------------------------------------------------------------
__global__ __launch_bounds__(1024) void sort_kernel(
    const int* __restrict__ len1, const int* __restrict__ key2,
    const int* __restrict__ len2,
    int* __restrict__ order1, int* __restrict__ len1s,
    int* __restrict__ order2, int* __restrict__ len2s,
    float4* __restrict__ pad0, float4* __restrict__ pad1,
    float4* __restrict__ pad2)
{
    if (blockIdx.x == 2) {
        const float4 z = {0.f, 0.f, 0.f, 0.f};
        const int t = threadIdx.x;
        #pragma unroll
        for (int j = 0; j < 2; ++j) {
            pad0[j * 1024 + t] = z;                  // 8192 floats
            pad1[j * 1024 + t] = z;
            pad2[j * 1024 + t] = z;
        }
        return;
    }
    __shared__ int hist[1024];
    __shared__ int scan[1024];
    const int t = threadIdx.x;
    const int* key = blockIdx.x ? key2 : len1;
    const int k = key[t];
    hist[t] = 0;
    __syncthreads();
    atomicAdd(&hist[k], 1);
    __syncthreads();
    scan[t] = hist[t];
    __syncthreads();
    for (int s = 1; s < 1024; s <<= 1) {
        const int v = scan[t] + ((t >= s) ? scan[t - s] : 0);
        __syncthreads();
        scan[t] = v;
        __syncthreads();
    }
    const int excl = scan[t] - hist[t];       // exclusive base for bin t
    __syncthreads();
    hist[t] = excl;                            // hist becomes cursor
    __syncthreads();
    const int pos = atomicAdd(&hist[k], 1);
    if (blockIdx.x == 0) {
        order1[pos] = t;
        len1s[pos]  = k;                       // len1 IS the key
    } else {
        order2[pos] = t;
        len2s[pos]  = len2[t];                 // monotone in d2 -> sorted
    }
}

// ---------------------------------------------------------------------------
// Middle gated layer (L1/L2): prefix-sparse, sorted-activation pipeline.
//   Input AX (sorted for L2, natural for L1) read SEQUENTIALLY in hot loop;
//   W gather (GI) confined to cold staging; 4 gates/iter (2 rows x 2 pos)
//   from one ds_read_b128; outputs written at SORTED position with the
//   next layer's A-value packed alongside.
// Grid 512 blocks x 1024 thr (16 waves, 2 blocks/CU); mirror map balances.
// ---------------------------------------------------------------------------
template<int I, bool GI>
__global__ __launch_bounds__(1024) void gated_mid(
    const float2* __restrict__ AX, const float* __restrict__ Ct,
    const float* __restrict__ W,  const float* __restrict__ Anext,
    const int* __restrict__ lenS, const int* __restrict__ ordRow,
    const int* __restrict__ ordIn, float2* __restrict__ outAX)
{
    const int bid = blockIdx.x;
    const int k   = (bid < 256) ? bid : (767 - bid);     // mirror balance
    const int R0  = 2 * k;
    const int tid = threadIdx.x;
    const int b   = tid & 63;
    const int wid = __builtin_amdgcn_readfirstlane(tid >> 6);   // 0..15

    __shared__ float2 mw2[I + 64];
    __shared__ float  red[16][2][64];

    const int len0 = lenS[R0], len1 = lenS[R0 + 1];
    const int r0 = ordRow[R0], r1 = ordRow[R0 + 1];
    const int Lmax = (len0 > len1) ? len0 : len1;
    const int Q = ((((Lmax + 1) >> 1) + 15) >> 4);       // pair-steps per wave
    const int S = Q << 5;                                // staged positions

    const float* __restrict__ w0p = W + (size_t)r0 * I;
    const float* __restrict__ w1p = W + (size_t)r1 * I;
    for (int p = tid; p < S; p += 1024) {
        const int ix = GI ? ((p < Lmax) ? ordIn[p] : 0) : p;
        float2 v;
        v.x = (p < len0) ? w0p[ix] : 0.f;
        v.y = (p < len1) ? w1p[ix] : 0.f;
        mw2[p] = v;
    }
    const float cc0 = Ct[r0 * 64 + b];
    const float cc1 = Ct[r1 * 64 + b];
    __syncthreads();

    const int base = (wid * Q) << 1;                     // position base (even)
    const float2* __restrict__ axp = AX + (size_t)base * 64 + b;
    const float2* __restrict__ mwp = mw2 + base;

    float a00 = 0.f, a01 = 0.f, a10 = 0.f, a11 = 0.f;
    #pragma unroll 4
    for (int t = 0; t < Q; ++t) {
        const float4 m4  = *(const float4*)(mwp + 2 * t);     // 16B-aligned
        const float2 axa = axp[(size_t)(2 * t) * 64];
        const float2 axb = axp[(size_t)(2 * t + 1) * 64];
        const float e0 = __builtin_amdgcn_exp2f(-(axa.x * cc0));
        const float e1 = __builtin_amdgcn_exp2f(-(axa.x * cc1));
        const float e2 = __builtin_amdgcn_exp2f(-(axb.x * cc0));
        const float e3 = __builtin_amdgcn_exp2f(-(axb.x * cc1));
        a00 = fmaf(__builtin_amdgcn_rcpf(1.f + e0), m4.x * axa.y, a00);
        a01 = fmaf(__builtin_amdgcn_rcpf(1.f + e1), m4.y * axa.y, a01);
        a10 = fmaf(__builtin_amdgcn_rcpf(1.f + e2), m4.z * axb.y, a10);
        a11 = fmaf(__builtin_amdgcn_rcpf(1.f + e3), m4.w * axb.y, a11);
    }

    red[wid][0][b] = a00 + a10;
    red[wid][1][b] = a01 + a11;
    __syncthreads();
    if (tid < 128) {
        const int oo = tid >> 6, bb = tid & 63;
        float v = 0.f;
        #pragma unroll
        for (int q = 0; q < 16; ++q) v += red[q][oo][bb];
        const int r = oo ? r1 : r0;                      // original row id
        float2 o2;
        o2.x = Anext[r * 64 + bb];                       // next-layer A (*L2E)
        o2.y = v;
        outAX[(size_t)(R0 + oo) * 64 + bb] = o2;         // sorted position
    }
}

// ---------------------------------------------------------------------------
// Final gated layer (L3): rows natural (len3 already ascending); input AX2s
// sorted by order2 (sequential reads); W2 gathered in staging only.
// Grid 512 blocks x 512 thr (8 waves, 2 blocks/CU); mirror map balances.
// ---------------------------------------------------------------------------
__global__ __launch_bounds__(512) void gated_fin(
    const float2* __restrict__ AX, const float* __restrict__ Ct,
    const float* __restrict__ W,  const int* __restrict__ len3,
    const int* __restrict__ ordIn, float* __restrict__ out)
{
    const int bid = blockIdx.x;
    const int r   = (bid < 256) ? bid : (767 - bid);     // mirror balance
    const int tid = threadIdx.x;
    const int b   = tid & 63;
    const int wid = __builtin_amdgcn_readfirstlane(tid >> 6);   // 0..7

    __shared__ float mw1[H2D + 64];
    __shared__ float red[8][64];

    const int len = len3[r];
    const int Q   = (((len + 3) >> 2) + 7) >> 3;         // quad-steps per wave
    const int S   = Q << 5;                              // staged positions

    const float* __restrict__ wp = W + (size_t)r * H2D;
    for (int p = tid; p < S; p += 512)
        mw1[p] = (p < len) ? wp[ordIn[p]] : 0.f;
    const float cc = Ct[r * 64 + b];
    __syncthreads();

    const int base = (wid * Q) << 2;                     // position base (x4)
    const float2* __restrict__ axp = AX + (size_t)base * 64 + b;
    const float*  __restrict__ mwp = mw1 + base;

    float a0 = 0.f, a1 = 0.f, a2 = 0.f, a3 = 0.f;
    #pragma unroll 4
    for (int t = 0; t < Q; ++t) {
        const float4 mm  = *(const float4*)(mwp + 4 * t);     // 16B-aligned
        const float2 x0 = axp[(size_t)(4 * t + 0) * 64];
        const float2 x1 = axp[(size_t)(4 * t + 1) * 64];
        const float2 x2 = axp[(size_t)(4 * t + 2) * 64];
        const float2 x3 = axp[(size_t)(4 * t + 3) * 64];
        const float e0 = __builtin_amdgcn_exp2f(-(x0.x * cc));
        const float e1 = __builtin_amdgcn_exp2f(-(x1.x * cc));
        const float e2 = __builtin_amdgcn_exp2f(-(x2.x * cc));
        const float e3 = __builtin_amdgcn_exp2f(-(x3.x * cc));
        a0 = fmaf(__builtin_amdgcn_rcpf(1.f + e0), mm.x * x0.y, a0);
        a1 = fmaf(__builtin_amdgcn_rcpf(1.f + e1), mm.y * x1.y, a1);
        a2 = fmaf(__builtin_amdgcn_rcpf(1.f + e2), mm.z * x2.y, a2);
        a3 = fmaf(__builtin_amdgcn_rcpf(1.f + e3), mm.w * x3.y, a3);
    }

    red[wid][b] = (a0 + a1) + (a2 + a3);
    __syncthreads();
    if (tid < 64) {
        float v = 0.f;
        #pragma unroll
        for (int q = 0; q < 8; ++q) v += red[q][tid];
        out[tid * NOUTD + r] = v;                        // (B, NOUT)
    }
}

// ---------------------------------------------------------------------------
extern "C" void kernel_launch(void* const* d_in, const int* in_sizes, int n_in,
                              void* d_out, int out_size, void* d_ws, size_t ws_size,
                              hipStream_t stream) {
    (void)in_sizes; (void)n_in; (void)out_size; (void)ws_size;
    const float* x   = (const float*)d_in[0];
    const float* u   = (const float*)d_in[1];
    const float* m0  = (const float*)d_in[2];
    const float* m1  = (const float*)d_in[3];
    const float* m2  = (const float*)d_in[4];
    const float* W0  = (const float*)d_in[5];
    const float* W1  = (const float*)d_in[6];
    const float* W2  = (const float*)d_in[7];
    const float* a0w = (const float*)d_in[8];  const float* a0b = (const float*)d_in[9];
    const float* b0w = (const float*)d_in[10]; const float* b0b = (const float*)d_in[11];
    const float* a1w = (const float*)d_in[12]; const float* a1b = (const float*)d_in[13];
    const float* b1w = (const float*)d_in[14]; const float* b1b = (const float*)d_in[15];
    const float* a2w = (const float*)d_in[16]; const float* a2b = (const float*)d_in[17];
    const float* b2w = (const float*)d_in[18]; const float* b2b = (const float*)d_in[19];

    float* ws   = (float*)d_ws;                // offsets in floats
    float* AX0  = ws;                          // (512+64)*64*2 = 73728
    float* AX1s = ws + 73728;                  // (1024+64)*64*2 = 139264
    float* AX2s = ws + 212992;                 // 139264
    float* A1x  = ws + 352256;                 // 1024*64 = 65536
    float* A2x  = ws + 417792;                 // 65536
    float* C0t  = ws + 483328;                 // 65536
    float* C1t  = ws + 548864;                 // 65536
    float* C2t  = ws + 614400;                 // 32768
    int*   ib   = (int*)(ws + 647168);
    int* len1   = ib;                          // 1024
    int* len2   = ib + 1024;                   // 1024
    int* len3   = ib + 2048;                   // 512
    int* key2   = ib + 2560;                   // 1024
    int* order1 = ib + 3584;                   // 1024
    int* len1s  = ib + 4608;                   // 1024
    int* order2 = ib + 5632;                   // 1024
    int* len2s  = ib + 6656;                   // 1024
    float* out  = (float*)d_out;

    // pad regions (positions [512,576) / [1024,1088) of the AX buffers)
    float4* pad0 = (float4*)(AX0  + 512 * 64 * 2);
    float4* pad1 = (float4*)(AX1s + 1024 * 64 * 2);
    float4* pad2 = (float4*)(AX2s + 1024 * 64 * 2);

    prep_kernel<<<504, 256, 0, stream>>>(x, u,
        a0w, a0b, b0w, b0b, a1w, a1b, b1w, b1b, a2w, a2b, b2w, b2b,
        m0, m1, m2,
        AX0, A1x, A2x, C0t, C1t, C2t,
        len1, len2, len3, key2);

    sort_kernel<<<3, 1024, 0, stream>>>(len1, key2, len2,
                                        order1, len1s, order2, len2s,
                                        pad0, pad1, pad2);

    // L1: I=512,  rows sorted by d1 (order1), input natural, out -> AX1s sorted
    gated_mid<NIN, false><<<512, 1024, 0, stream>>>(
        (const float2*)AX0, C0t, W0, A1x, len1s, order1, nullptr,
        (float2*)AX1s);
    // L2: I=1024, rows sorted by d2 (order2), input AX1s sequential,
    //     W1 cols gathered by order1 in staging, out -> AX2s sorted
    gated_mid<H1D, true><<<512, 1024, 0, stream>>>(
        (const float2*)AX1s, C1t, W1, A2x, len2s, order2, order1,
        (float2*)AX2s);
    // L3: rows natural (len3 ascending), input AX2s sequential,
    //     W2 cols gathered by order2 in staging, out -> (B, NOUT)
    gated_fin<<<512, 512, 0, stream>>>(
        (const float2*)AX2s, C2t, W2, len3, order2, out);
}